// Round 5
// baseline (217.645 us; speedup 1.0000x reference)
//
#include <hip/hip_runtime.h>

#define N_RAYS    65536
#define N_SAMPLES 128

typedef float vfloat4 __attribute__((ext_vector_type(4)));

// 16 lanes per ray, 8 samples per lane, 4 rays per wave.
// weight[j] = max(sig_j - sig_{j+1}, 0) / sig_0 (telescoped transmittance),
// weight[0] = weight[127] = 0.
// All bulk traffic is nontemporal (zero reuse; bypass L2/L3 allocation).
__global__ __launch_bounds__(256) void neus_render_kernel(
    const vfloat4* __restrict__ sdf4,      // [R, S/4]
    const vfloat4* __restrict__ color4,    // [R, S*3/4]
    const vfloat4* __restrict__ z4,        // [R, S/4]
    const float*  __restrict__ s_ptr,      // [1]
    const float*  __restrict__ bg,         // [3]
    float* __restrict__ pixel_out,         // [R, 3]
    float* __restrict__ invdepth_out,      // [R]
    vfloat4* __restrict__ weight4_out)     // [R, S/4]
{
    const int tid  = blockIdx.x * blockDim.x + threadIdx.x;
    const int lane = threadIdx.x & 63;
    const int sub  = lane & 15;            // lane position within its ray
    const int ray  = (tid >> 6) * 4 + (lane >> 4);

    const float s = s_ptr[0];

    const size_t rowq = (size_t)ray * (N_SAMPLES / 4);   // float4 index of row
    const int q0 = sub * 2;                              // first owned float4

    // ---- issue all loads up front (independent float4, nontemporal) ----
    const vfloat4 sd0 = __builtin_nontemporal_load(&sdf4[rowq + q0]);
    const vfloat4 sd1 = __builtin_nontemporal_load(&sdf4[rowq + q0 + 1]);
    const vfloat4 zz0 = __builtin_nontemporal_load(&z4[rowq + q0]);
    const vfloat4 zz1 = __builtin_nontemporal_load(&z4[rowq + q0 + 1]);
    const size_t crowq = (size_t)ray * (N_SAMPLES * 3 / 4);
    vfloat4 c[6];
    #pragma unroll
    for (int i = 0; i < 6; ++i)
        c[i] = __builtin_nontemporal_load(&color4[crowq + sub * 6 + i]);

    // ---- sigmoids of the 8 owned samples ----
    float sg[8];
    {
        const float sdv[8] = {sd0.x, sd0.y, sd0.z, sd0.w,
                              sd1.x, sd1.y, sd1.z, sd1.w};
        #pragma unroll
        for (int k = 0; k < 8; ++k)
            sg[k] = __builtin_amdgcn_rcpf(1.0f + __expf(-sdv[k] * s));
    }

    // neighbor lane's first sigmoid = sample j0+8; ray's sample-0 sigmoid
    const float sig_nb    = __shfl_down(sg[0], 1);           // junk at sub==15 (unused)
    const float sig_first = __shfl(sg[0], lane & 48);        // lane 16*(lane>>4)
    const float inv0 = __builtin_amdgcn_rcpf(sig_first);

    // ---- weights ----
    float w[8];
    #pragma unroll
    for (int k = 0; k < 7; ++k) w[k] = fmaxf(sg[k] - sg[k + 1], 0.0f) * inv0;
    w[7] = fmaxf(sg[7] - sig_nb, 0.0f) * inv0;
    if (sub == 0)  w[0] = 0.0f;    // weight[0]   = 0
    if (sub == 15) w[7] = 0.0f;    // weight[127] = 0

    {
        vfloat4 wq0 = {w[0], w[1], w[2], w[3]};
        vfloat4 wq1 = {w[4], w[5], w[6], w[7]};
        __builtin_nontemporal_store(wq0, &weight4_out[rowq + q0]);
        __builtin_nontemporal_store(wq1, &weight4_out[rowq + q0 + 1]);
    }

    // ---- per-lane partials ----
    const float zv[8] = {zz0.x, zz0.y, zz0.z, zz0.w,
                         zz1.x, zz1.y, zz1.z, zz1.w};
    const float* cf = (const float*)c;     // 24 consecutive floats: c[k][rgb]
    float pr = 0.f, pg = 0.f, pb = 0.f, invd = 0.f, wsum = 0.f;
    #pragma unroll
    for (int k = 0; k < 8; ++k) {
        invd += w[k] * __builtin_amdgcn_rcpf(zv[k]);
        pr   += w[k] * cf[3 * k + 0];
        pg   += w[k] * cf[3 * k + 1];
        pb   += w[k] * cf[3 * k + 2];
        wsum += w[k];
    }

    // ---- reduction across the 16 lanes of this ray (xor masks stay in-group) ----
    #pragma unroll
    for (int m = 8; m >= 1; m >>= 1) {
        pr   += __shfl_xor(pr, m);
        pg   += __shfl_xor(pg, m);
        pb   += __shfl_xor(pb, m);
        invd += __shfl_xor(invd, m);
        wsum += __shfl_xor(wsum, m);
    }

    if (sub == 0) {
        const float resid = 1.0f - wsum;
        pixel_out[ray * 3 + 0] = pr + resid * bg[0];
        pixel_out[ray * 3 + 1] = pg + resid * bg[1];
        pixel_out[ray * 3 + 2] = pb + resid * bg[2];
        invdepth_out[ray] = invd;
    }
}

extern "C" void kernel_launch(void* const* d_in, const int* in_sizes, int n_in,
                              void* d_out, int out_size, void* d_ws, size_t ws_size,
                              hipStream_t stream) {
    const vfloat4* sdf   = (const vfloat4*)d_in[0];
    const vfloat4* color = (const vfloat4*)d_in[1];
    const vfloat4* z     = (const vfloat4*)d_in[2];
    const float*   s     = (const float*)d_in[3];
    const float*   bg    = (const float*)d_in[4];

    float* out      = (float*)d_out;
    float* pixel    = out;                                  // [R,3]
    float* invdepth = out + (size_t)N_RAYS * 3;             // [R]
    vfloat4* weight = (vfloat4*)(out + (size_t)N_RAYS * 3 + N_RAYS);  // [R,S]

    // 16 lanes per ray: 65536*16 threads -> 4096 blocks of 256
    const int block = 256;
    const int grid  = (N_RAYS * 16) / block;
    neus_render_kernel<<<grid, block, 0, stream>>>(
        sdf, color, z, s, bg, pixel, invdepth, weight);
}

// Round 6
// 194.632 us; speedup vs baseline: 1.1182x; 1.1182x over previous
//
#include <hip/hip_runtime.h>

#define N_RAYS    65536
#define N_SAMPLES 128
#define RPB       16   // rays per block (256 threads: 4 waves, 4 rays/wave, 16 lanes/ray)

typedef float vfloat4 __attribute__((ext_vector_type(4)));

// Lane owns two sample quads: A = samples [4*sub, 4*sub+3], B = samples [64+4*sub, 64+4*sub+3].
// weight[j] = max(sig_j - sig_{j+1}, 0) / sig_0 (telescoped transmittance); w[0]=w[127]=0.
// All bulk traffic nontemporal AND lane-contiguous: every 64B line touched by
// exactly one instruction exactly once (no reuse for the nt bypass to forfeit).
__global__ __launch_bounds__(256) void neus_render_kernel(
    const vfloat4* __restrict__ sdf4,      // [R, 32]
    const vfloat4* __restrict__ color4,    // [R, 96]
    const vfloat4* __restrict__ z4,        // [R, 32]
    const float*  __restrict__ s_ptr,      // [1]
    const float*  __restrict__ bg,         // [3]
    float* __restrict__ pixel_out,         // [R, 3]
    float* __restrict__ invdepth_out,      // [R]
    vfloat4* __restrict__ weight4_out)     // [R, 32]
{
    __shared__ vfloat4 cbuf[RPB * 96];     // 24 KB color slab for this block's 16 rays

    const int t    = threadIdx.x;
    const int lane = t & 63;
    const int sub  = lane & 15;            // lane within its ray
    const int grp  = lane & 48;            // base lane of this ray's 16-lane group
    const int ray  = blockIdx.x * RPB + (t >> 4);

    // ---- issue ALL global loads up front ----
    // color: flat stream, 4 KB fully-dense per instruction per block
    const vfloat4* cg = color4 + (size_t)blockIdx.x * (RPB * 96);
    vfloat4 cl[6];
    #pragma unroll
    for (int i = 0; i < 6; ++i)
        cl[i] = __builtin_nontemporal_load(&cg[t + 256 * i]);

    // sdf / z: quad ownership -> each instr reads 4x256B dense segments
    const size_t rq = (size_t)ray * 32;
    const vfloat4 sdA = __builtin_nontemporal_load(&sdf4[rq + sub]);
    const vfloat4 sdB = __builtin_nontemporal_load(&sdf4[rq + 16 + sub]);
    const vfloat4 zA  = __builtin_nontemporal_load(&z4[rq + sub]);
    const vfloat4 zB  = __builtin_nontemporal_load(&z4[rq + 16 + sub]);

    const float s = s_ptr[0];

    // ---- sigmoids of the 8 owned samples ----
    float sgA[4], sgB[4];
    {
        const float a[4] = {sdA.x, sdA.y, sdA.z, sdA.w};
        const float b[4] = {sdB.x, sdB.y, sdB.z, sdB.w};
        #pragma unroll
        for (int k = 0; k < 4; ++k) {
            sgA[k] = __builtin_amdgcn_rcpf(1.0f + __expf(-a[k] * s));
            sgB[k] = __builtin_amdgcn_rcpf(1.0f + __expf(-b[k] * s));
        }
    }

    // neighbor sigmoids: sig(4*sub+4) and sig(64+4*sub+4)
    const int   src  = grp | ((sub + 1) & 15);
    const float aN   = __shfl(sgA[0], src);
    const float bN   = __shfl(sgB[0], src);
    const float nxtA = (sub == 15) ? bN : aN;   // sub==15 wraps to sample 64
    const float sig0 = __shfl(sgA[0], grp);
    const float inv0 = __builtin_amdgcn_rcpf(sig0);

    // ---- weights ----
    float wA[4], wB[4];
    #pragma unroll
    for (int k = 0; k < 3; ++k) {
        wA[k] = fmaxf(sgA[k] - sgA[k + 1], 0.0f) * inv0;
        wB[k] = fmaxf(sgB[k] - sgB[k + 1], 0.0f) * inv0;
    }
    wA[3] = fmaxf(sgA[3] - nxtA, 0.0f) * inv0;
    wB[3] = fmaxf(sgB[3] - bN,   0.0f) * inv0;
    if (sub == 0)  wA[0] = 0.0f;   // weight[0]
    if (sub == 15) wB[3] = 0.0f;   // weight[127]

    {
        vfloat4 wqA = {wA[0], wA[1], wA[2], wA[3]};
        vfloat4 wqB = {wB[0], wB[1], wB[2], wB[3]};
        __builtin_nontemporal_store(wqA, &weight4_out[rq + sub]);
        __builtin_nontemporal_store(wqB, &weight4_out[rq + 16 + sub]);
    }

    // ---- inverse-depth & weight-sum partials (color-independent) ----
    const float za[4] = {zA.x, zA.y, zA.z, zA.w};
    const float zb[4] = {zB.x, zB.y, zB.z, zB.w};
    float invd = 0.f, wsum = 0.f;
    #pragma unroll
    for (int k = 0; k < 4; ++k) {
        invd += wA[k] * __builtin_amdgcn_rcpf(za[k]);
        invd += wB[k] * __builtin_amdgcn_rcpf(zb[k]);
        wsum += wA[k] + wB[k];
    }

    // ---- stage color through LDS to redistribute to compute ownership ----
    #pragma unroll
    for (int i = 0; i < 6; ++i) cbuf[t + 256 * i] = cl[i];
    __syncthreads();

    const int qb = (t >> 4) * 96 + 3 * sub;      // this lane's first color float4 in its row
    const vfloat4 cA0 = cbuf[qb],      cA1 = cbuf[qb + 1],  cA2 = cbuf[qb + 2];
    const vfloat4 cB0 = cbuf[qb + 48], cB1 = cbuf[qb + 49], cB2 = cbuf[qb + 50];

    float pr, pg, pb;
    pr  = wA[0] * cA0.x + wA[1] * cA0.w + wA[2] * cA1.z + wA[3] * cA2.y;
    pg  = wA[0] * cA0.y + wA[1] * cA1.x + wA[2] * cA1.w + wA[3] * cA2.z;
    pb  = wA[0] * cA0.z + wA[1] * cA1.y + wA[2] * cA2.x + wA[3] * cA2.w;
    pr += wB[0] * cB0.x + wB[1] * cB0.w + wB[2] * cB1.z + wB[3] * cB2.y;
    pg += wB[0] * cB0.y + wB[1] * cB1.x + wB[2] * cB1.w + wB[3] * cB2.z;
    pb += wB[0] * cB0.z + wB[1] * cB1.y + wB[2] * cB2.x + wB[3] * cB2.w;

    // ---- reduce across the 16 lanes of this ray ----
    #pragma unroll
    for (int m = 8; m >= 1; m >>= 1) {
        pr   += __shfl_xor(pr, m);
        pg   += __shfl_xor(pg, m);
        pb   += __shfl_xor(pb, m);
        invd += __shfl_xor(invd, m);
        wsum += __shfl_xor(wsum, m);
    }

    if (sub == 0) {
        const float resid = 1.0f - wsum;
        pixel_out[ray * 3 + 0] = pr + resid * bg[0];
        pixel_out[ray * 3 + 1] = pg + resid * bg[1];
        pixel_out[ray * 3 + 2] = pb + resid * bg[2];
        invdepth_out[ray] = invd;
    }
}

extern "C" void kernel_launch(void* const* d_in, const int* in_sizes, int n_in,
                              void* d_out, int out_size, void* d_ws, size_t ws_size,
                              hipStream_t stream) {
    const vfloat4* sdf   = (const vfloat4*)d_in[0];
    const vfloat4* color = (const vfloat4*)d_in[1];
    const vfloat4* z     = (const vfloat4*)d_in[2];
    const float*   s     = (const float*)d_in[3];
    const float*   bg    = (const float*)d_in[4];

    float* out      = (float*)d_out;
    float* pixel    = out;                                            // [R,3]
    float* invdepth = out + (size_t)N_RAYS * 3;                       // [R]
    vfloat4* weight = (vfloat4*)(out + (size_t)N_RAYS * 3 + N_RAYS);  // [R,S]

    const int block = 256;
    const int grid  = N_RAYS / RPB;   // 4096
    neus_render_kernel<<<grid, block, 0, stream>>>(
        sdf, color, z, s, bg, pixel, invdepth, weight);
}